// Round 1
// baseline (872.013 us; speedup 1.0000x reference)
//
#include <hip/hip_runtime.h>
#include <hip/hip_fp16.h>

#define NN 100000
#define EE 1200000
#define DD 64
#define CC 40
#define KK 16
#define BSZ 196                          // nodes per sort bucket
#define NBK 512                          // buckets (512*196 = 100352 >= NN)
#define TCAP 3072                        // tmp capacity per bucket (mean 2352, ~15 sigma)
#define EPB 4096                         // edges per phase-A block
#define ABLK ((EE + EPB - 1) / EPB)      // 293

// SoA plane layout: x[q*NN + n] is a float4 of 8 halves = channels 8q..8q+7 of node n.
// spmm runs as 3 temporal passes (planes {0,1},{2,3},{4}) so the concurrent gather
// working set is <=3.2MB and stays resident in each XCD's 4MB L2 (vs 8MB thrash).
#define NB2 3125                         // blocks per 2-plane pass (32 nodes, 2 lanes/node)
#define NB1 1563                         // blocks for plane-4 pass (64 nodes, 1 lane/node)
#define GBLK2 (2 * NB2 + NB1)            // 7813

struct __align__(8) ERec { int c; float w; };

// ---------- cursor init: cursor[b] = b*TCAP ----------
__global__ __launch_bounds__(512) void curinit_kernel(int* __restrict__ cursor) {
    int b = threadIdx.x;
    if (b < NBK) cursor[b] = b * TCAP;
}

// ---------- sort phase A: LDS-bin 4096 edges into 512 buckets, write runs ----------
__global__ __launch_bounds__(256) void sortA_kernel(const int* __restrict__ src,
                                                    const int* __restrict__ dst,
                                                    int* __restrict__ cursor,
                                                    int2* __restrict__ tmp) {
    __shared__ int2 stg[EPB];                 // 32KB
    __shared__ int hist[NBK], loff[NBK], lcur[NBK], gbase[NBK];  // 8KB
    int t = threadIdx.x;
    long e0 = (long)blockIdx.x * EPB;
    int n = (int)((EE - e0 < EPB) ? (EE - e0) : EPB);
    for (int j = t; j < NBK; j += 256) hist[j] = 0;
    __syncthreads();
    int d[16], sx[16];
#pragma unroll
    for (int j = 0; j < 16; ++j) {
        int i = t + j * 256;
        if (i < n) {
            d[j] = dst[e0 + i];
            sx[j] = src[e0 + i];
            atomicAdd(&hist[d[j] / BSZ], 1);
        } else d[j] = -1;
    }
    __syncthreads();
    int c0 = hist[2 * t], c1 = hist[2 * t + 1];
    int s2 = c0 + c1;
    __syncthreads();
    loff[t] = s2;
    __syncthreads();
    for (int off = 1; off < 256; off <<= 1) {
        int u = (t >= off) ? loff[t - off] : 0;
        __syncthreads();
        loff[t] += u;
        __syncthreads();
    }
    int excl = loff[t] - s2;
    __syncthreads();
    loff[2 * t] = excl;          loff[2 * t + 1] = excl + c0;
    lcur[2 * t] = excl;          lcur[2 * t + 1] = excl + c0;
    gbase[2 * t]     = atomicAdd(&cursor[2 * t], c0);
    gbase[2 * t + 1] = atomicAdd(&cursor[2 * t + 1], c1);
    __syncthreads();
#pragma unroll
    for (int j = 0; j < 16; ++j) {
        if (d[j] >= 0) {
            int b = d[j] / BSZ;
            int p = atomicAdd(&lcur[b], 1);
            stg[p] = make_int2(d[j], sx[j]);
        }
    }
    __syncthreads();
    for (int i = t; i < n; i += 256) {
        int2 r = stg[i];
        int b = r.x / BSZ;
        int pos = gbase[b] + (i - loff[b]);
        if (pos < (b + 1) * TCAP) tmp[pos] = r;  // overflow guard (never hit, 15 sigma)
    }
}

// ---------- bucket-base scan ----------
__global__ __launch_bounds__(512) void bscan_kernel(const int* __restrict__ cursor,
                                                    int* __restrict__ bbase,
                                                    int* __restrict__ row_ptr) {
    __shared__ int sm[512];
    int t = threadIdx.x;
    int v = (t < NBK) ? (cursor[t] - t * TCAP) : 0;
    sm[t] = v;
    __syncthreads();
    for (int off = 1; off < 512; off <<= 1) {
        int u = (t >= off) ? sm[t - off] : 0;
        __syncthreads();
        sm[t] += u;
        __syncthreads();
    }
    if (t < NBK) bbase[t] = sm[t] - v;
    if (t == 511) row_ptr[NN] = sm[511];  // == EE
}

// ---------- sort phase B: counting sort within bucket ----------
__global__ __launch_bounds__(256) void sortB_kernel(const int2* __restrict__ tmp,
                                                    const int* __restrict__ cursor,
                                                    const int* __restrict__ bbase,
                                                    float* __restrict__ dinv,
                                                    int* __restrict__ row_ptr,
                                                    int2* __restrict__ er2) {
    __shared__ int2 se[TCAP];     // 24KB
    __shared__ int2 so[TCAP];     // 24KB
    __shared__ int hist[256], lcur[256];
    int b = blockIdx.x;
    int n0 = b * BSZ;
    if (n0 >= NN) return;
    int n1 = n0 + BSZ; if (n1 > NN) n1 = NN;
    int nb = n1 - n0;
    int t = threadIdx.x;
    int cnt = cursor[b] - b * TCAP;
    int base = bbase[b];
    hist[t] = 0;
    __syncthreads();
    for (int i = t; i < cnt; i += 256) {
        int2 r = tmp[b * TCAP + i];
        se[i] = r;
        atomicAdd(&hist[r.x - n0], 1);
    }
    __syncthreads();
    if (t < nb) dinv[n0 + t] = rsqrtf((float)(hist[t] + 1));  // +1 self-loop
    int v = hist[t];
    lcur[t] = v;
    __syncthreads();
    for (int off = 1; off < 256; off <<= 1) {
        int u = (t >= off) ? lcur[t - off] : 0;
        __syncthreads();
        lcur[t] += u;
        __syncthreads();
    }
    int excl = lcur[t] - v;
    __syncthreads();
    lcur[t] = excl;
    if (t < nb) row_ptr[n0 + t] = base + excl;
    __syncthreads();
    for (int i = t; i < cnt; i += 256) {
        int2 r = se[i];
        int ln = r.x - n0;
        int pos = atomicAdd(&lcur[ln], 1);
        so[pos] = make_int2(r.y, r.x);  // (src, dst)
    }
    __syncthreads();
    for (int i = t; i < cnt; i += 256) er2[base + i] = so[i];  // coalesced
}

// ---------- weight fill ----------
__global__ __launch_bounds__(256) void wfill_kernel(const int2* __restrict__ er2,
                                                    const float* __restrict__ dinv,
                                                    int2* __restrict__ er) {
    int i = blockIdx.x * 256 + threadIdx.x;
    if (i >= EE) return;
    int2 r = er2[i];
    float w = dinv[r.y] * dinv[r.x];
    er[i] = make_int2(r.x, __float_as_int(w));
}

// ---------- projection: y0 = feat @ W^T (LDS-tiled, coalesced), SoA-plane output
__global__ __launch_bounds__(256) void proj_kernel(const float4* __restrict__ feat4,
                                                   const float* __restrict__ W,
                                                   float4* __restrict__ y0) {
    __shared__ float smW[CC * 68];   // 10.9KB
    __shared__ float smF[64 * 68];   // 17.4KB
    __shared__ float smO[64 * 42];   // 10.8KB
    int t = threadIdx.x;
    for (int j = t; j < CC * 16; j += 256) {
        int c = j >> 4, q = j & 15;
        *(float4*)(smW + c * 68 + q * 4) = ((const float4*)W)[j];
    }
    int n0 = blockIdx.x * 64;
    for (int j = t; j < 64 * 16; j += 256) {
        int r = j >> 4, q = j & 15;
        if (n0 + r < NN)
            *(float4*)(smF + r * 68 + q * 4) = feat4[(size_t)(n0 + r) * 16 + q];
    }
    __syncthreads();
    int ln = t >> 2, c0 = (t & 3) * 10;
    int node = n0 + ln;
    float acc[10];
#pragma unroll
    for (int c = 0; c < 10; ++c) acc[c] = 0.f;
    if (node < NN) {
#pragma unroll
        for (int db = 0; db < 16; ++db) {
            float4 fv = *(const float4*)(smF + ln * 68 + db * 4);
#pragma unroll
            for (int c = 0; c < 10; ++c) {
                float4 wv = *(const float4*)(smW + (c0 + c) * 68 + db * 4);
                acc[c] = fmaf(fv.x, wv.x, acc[c]);
                acc[c] = fmaf(fv.y, wv.y, acc[c]);
                acc[c] = fmaf(fv.z, wv.z, acc[c]);
                acc[c] = fmaf(fv.w, wv.w, acc[c]);
            }
        }
    }
#pragma unroll
    for (int c = 0; c < 10; ++c) smO[ln * 42 + c0 + c] = acc[c];
    __syncthreads();
    // store: q = plane (slow), r = node (fast) -> coalesced per-plane bursts
    for (int j = t; j < 64 * 5; j += 256) {
        int r = j & 63, q = j >> 6;
        if (n0 + r < NN) {
            const float* s = smO + r * 42 + q * 8;
            float4 ov;
            __half2* op = (__half2*)&ov;
            op[0] = __floats2half2_rn(s[0], s[1]);
            op[1] = __floats2half2_rn(s[2], s[3]);
            op[2] = __floats2half2_rn(s[4], s[5]);
            op[3] = __floats2half2_rn(s[6], s[7]);
            y0[(size_t)q * NN + (n0 + r)] = ov;
        }
    }
}

// decode float4-of-8-halves into 8 floats
#define DEC8(V, F0, F1, F2, F3)                                             \
    const __half2* hp_##F0 = (const __half2*)&(V);                          \
    float2 F0 = __half22float2(hp_##F0[0]), F1 = __half22float2(hp_##F0[1]);\
    float2 F2 = __half22float2(hp_##F0[2]), F3 = __half22float2(hp_##F0[3]);

#define ACC8(R, V)                                                          \
    {                                                                       \
        DEC8(V, f0, f1, f2, f3)                                             \
        a0 = fmaf((R).w, f0.x, a0); a1 = fmaf((R).w, f0.y, a1);             \
        a2 = fmaf((R).w, f1.x, a2); a3 = fmaf((R).w, f1.y, a3);             \
        a4 = fmaf((R).w, f2.x, a4); a5 = fmaf((R).w, f2.y, a5);             \
        a6 = fmaf((R).w, f3.x, a6); a7 = fmaf((R).w, f3.y, a7);             \
    }

// edge loop, unroll x8 then x4 then singles — up to 8 gathers in flight/lane.
// XP is the plane-offset source pointer; gathers are plain xp[src].
#define EDGE_LOOP(XP)                                                       \
    int e = beg;                                                            \
    int e8 = beg + ((end - beg) & ~7);                                      \
    for (; e < e8; e += 8) {                                                \
        ERec r0 = er[e], r1 = er[e + 1], r2 = er[e + 2], r3 = er[e + 3];    \
        ERec r4 = er[e + 4], r5 = er[e + 5], r6 = er[e + 6], r7 = er[e + 7];\
        float4 v0 = (XP)[r0.c];                                             \
        float4 v1 = (XP)[r1.c];                                             \
        float4 v2 = (XP)[r2.c];                                             \
        float4 v3 = (XP)[r3.c];                                             \
        float4 v4 = (XP)[r4.c];                                             \
        float4 v5 = (XP)[r5.c];                                             \
        float4 v6 = (XP)[r6.c];                                             \
        float4 v7 = (XP)[r7.c];                                             \
        ACC8(r0, v0); ACC8(r1, v1); ACC8(r2, v2); ACC8(r3, v3);             \
        ACC8(r4, v4); ACC8(r5, v5); ACC8(r6, v6); ACC8(r7, v7);             \
    }                                                                       \
    int e4 = e + ((end - e) & ~3);                                          \
    for (; e < e4; e += 4) {                                                \
        ERec r0 = er[e], r1 = er[e + 1], r2 = er[e + 2], r3 = er[e + 3];    \
        float4 v0 = (XP)[r0.c];                                             \
        float4 v1 = (XP)[r1.c];                                             \
        float4 v2 = (XP)[r2.c];                                             \
        float4 v3 = (XP)[r3.c];                                             \
        ACC8(r0, v0); ACC8(r1, v1); ACC8(r2, v2); ACC8(r3, v3);             \
    }                                                                       \
    for (; e < end; ++e) {                                                  \
        ERec r = er[e];                                                     \
        float4 v = (XP)[r.c];                                               \
        ACC8(r, v);                                                         \
    }

// block index -> (node g, plane q). Passes ordered by blockIdx so in-order
// dispatch keeps one plane-pair (<=3.2MB) as the live L2 working set.
// Returns false for tail lanes past NN.
__device__ __forceinline__ bool bmap(int b, int lane, int& g, int& q) {
    if (b < 2 * NB2) {
        int pb = (b >= NB2) ? 1 : 0;
        g = (b - pb * NB2) * 32 + (lane >> 1);
        q = pb * 2 + (lane & 1);
        return true;                 // 3125*32 == NN exactly
    }
    g = (b - 2 * NB2) * 64 + lane;
    q = 4;
    return g < NN;
}

// ---------- SpMM propagate step: x_out = A_hat * x (plane-pass temporal split)
__global__ __launch_bounds__(64) void spmm_prop(
    const float4* __restrict__ x, float4* __restrict__ x_out,
    const int* __restrict__ row_ptr, const ERec* __restrict__ er,
    const float* __restrict__ dinv) {
    int g, q;
    if (!bmap(blockIdx.x, threadIdx.x, g, q)) return;
    const float4* xp = x + (size_t)q * NN;
    int beg = row_ptr[g], end = row_ptr[g + 1];
    float di = dinv[g];
    float w0 = di * di;
    float4 sv = xp[g];
    float a0, a1, a2, a3, a4, a5, a6, a7;
    {
        DEC8(sv, f0, f1, f2, f3)
        a0 = w0 * f0.x; a1 = w0 * f0.y; a2 = w0 * f1.x; a3 = w0 * f1.y;
        a4 = w0 * f2.x; a5 = w0 * f2.y; a6 = w0 * f3.x; a7 = w0 * f3.y;
    }
    EDGE_LOOP(xp)
    float4 ov;
    __half2* op = (__half2*)&ov;
    op[0] = __floats2half2_rn(a0, a1);
    op[1] = __floats2half2_rn(a2, a3);
    op[2] = __floats2half2_rn(a4, a5);
    op[3] = __floats2half2_rn(a6, a7);
    x_out[(size_t)q * NN + g] = ov;
}

// ---------- final step: acc = A*x15 (= x16), then
// out = C16*x16 + C15*x15 + C14*x14 + C13*x13 + FC*y0 + bias
// (c_k = 0.95/16^(17-k); k<=12 terms <= ~3e-6 -> dropped)
__global__ __launch_bounds__(64) void spmm_final(
    const float4* __restrict__ x,     // x15 (gather source)
    const float4* __restrict__ x13p,
    const float4* __restrict__ x14p,
    const float4* __restrict__ y0,
    const float* __restrict__ bias,
    const int* __restrict__ row_ptr, const ERec* __restrict__ er,
    const float* __restrict__ dinv, float* __restrict__ outp) {
    int g, q;
    if (!bmap(blockIdx.x, threadIdx.x, g, q)) return;
    const float4* xp = x + (size_t)q * NN;
    size_t idx = (size_t)q * NN + g;
    int beg = row_ptr[g], end = row_ptr[g + 1];
    float di = dinv[g];
    float w0 = di * di;
    float4 sv = xp[g];
    float s0, s1, s2, s3, s4, s5, s6, s7;
    float a0, a1, a2, a3, a4, a5, a6, a7;
    {
        DEC8(sv, f0, f1, f2, f3)
        s0 = f0.x; s1 = f0.y; s2 = f1.x; s3 = f1.y;
        s4 = f2.x; s5 = f2.y; s6 = f3.x; s7 = f3.y;
        a0 = w0 * s0; a1 = w0 * s1; a2 = w0 * s2; a3 = w0 * s3;
        a4 = w0 * s4; a5 = w0 * s5; a6 = w0 * s6; a7 = w0 * s7;
    }
    EDGE_LOOP(xp)
    const float C16 = 0.95f / 16.0f;
    const float C15 = 0.95f / 256.0f;
    const float C14 = 0.95f / 4096.0f;
    const float C13 = 0.95f / 65536.0f;
    const float FC  = 0.05f / 15.0f;
    float o0 = C16 * a0 + C15 * s0, o1 = C16 * a1 + C15 * s1;
    float o2 = C16 * a2 + C15 * s2, o3 = C16 * a3 + C15 * s3;
    float o4 = C16 * a4 + C15 * s4, o5 = C16 * a5 + C15 * s5;
    float o6 = C16 * a6 + C15 * s6, o7 = C16 * a7 + C15 * s7;
#define ADD8(P, CF)                                                         \
    {                                                                       \
        float4 v = (P)[idx];                                                \
        DEC8(v, f0, f1, f2, f3)                                             \
        o0 = fmaf((CF), f0.x, o0); o1 = fmaf((CF), f0.y, o1);               \
        o2 = fmaf((CF), f1.x, o2); o3 = fmaf((CF), f1.y, o3);               \
        o4 = fmaf((CF), f2.x, o4); o5 = fmaf((CF), f2.y, o5);               \
        o6 = fmaf((CF), f3.x, o6); o7 = fmaf((CF), f3.y, o7);               \
    }
    ADD8(x14p, C14)
    ADD8(x13p, C13)
    ADD8(y0, FC)
#undef ADD8
    const float4* b4 = (const float4*)(bias + q * 8);
    float4 bb0 = b4[0], bb1 = b4[1];
    float4 w0v = make_float4(o0 + bb0.x, o1 + bb0.y, o2 + bb0.z, o3 + bb0.w);
    float4 w1v = make_float4(o4 + bb1.x, o5 + bb1.y, o6 + bb1.z, o7 + bb1.w);
    float4* op = (float4*)(outp + (size_t)g * CC + q * 8);
    op[0] = w0v; op[1] = w1v;
}

extern "C" void kernel_launch(void* const* d_in, const int* in_sizes, int n_in,
                              void* d_out, int out_size, void* d_ws, size_t ws_size,
                              hipStream_t stream) {
    const float* feat = (const float*)d_in[0];
    const float* W    = (const float*)d_in[1];
    const float* b    = (const float*)d_in[2];
    const int*   src  = (const int*)d_in[3];
    const int*   dst  = (const int*)d_in[4];
    float* out = (float*)d_out;

    char* p = (char*)d_ws;
    auto alloc = [&](size_t bytes) {
        char* r = p;
        p += (bytes + 255) & ~(size_t)255;
        return r;
    };
    float*   dinv    = (float*)alloc((size_t)NN * sizeof(float));
    int*     row_ptr = (int*)alloc((size_t)(NN + 1) * sizeof(int));
    int*     cursor  = (int*)alloc((size_t)NBK * sizeof(int));
    int*     bbase   = (int*)alloc((size_t)NBK * sizeof(int));
    int2*    tmp     = (int2*)alloc((size_t)NBK * TCAP * sizeof(int2));  // 12.6MB
    int2*    er2     = (int2*)alloc((size_t)EE * sizeof(int2));          // 9.6MB
    int2*    er      = (int2*)alloc((size_t)EE * sizeof(int2));          // 9.6MB
    float4*  y0      = (float4*)alloc((size_t)NN * 5 * sizeof(float4));  // 8MB
    float4*  xa      = (float4*)alloc((size_t)NN * 5 * sizeof(float4));  // 8MB
    float4*  xb      = (float4*)alloc((size_t)NN * 5 * sizeof(float4));  // 8MB
    float4*  x13b    = (float4*)alloc((size_t)NN * 5 * sizeof(float4));  // 8MB
    float4*  x14b    = (float4*)alloc((size_t)NN * 5 * sizeof(float4));  // 8MB
    float4*  x15b    = (float4*)alloc((size_t)NN * 5 * sizeof(float4));  // 8MB

    curinit_kernel<<<1, 512, 0, stream>>>(cursor);
    sortA_kernel<<<ABLK, 256, 0, stream>>>(src, dst, cursor, tmp);
    bscan_kernel<<<1, 512, 0, stream>>>(cursor, bbase, row_ptr);
    sortB_kernel<<<NBK, 256, 0, stream>>>(tmp, cursor, bbase, dinv, row_ptr, er2);
    wfill_kernel<<<(EE + 255) / 256, 256, 0, stream>>>(er2, dinv, er);
    proj_kernel<<<(NN + 63) / 64, 256, 0, stream>>>((const float4*)feat, W, y0);

    // j = 0..11: ping-pong xa/xb (produce x1..x12; x<=12 don't feed the output)
    const float4* xs = y0;
    for (int j = 0; j < 12; ++j) {
        float4* xd = (j & 1) ? xb : xa;
        spmm_prop<<<GBLK2, 64, 0, stream>>>(xs, xd, row_ptr, (const ERec*)er, dinv);
        xs = xd;
    }
    // x13, x14, x15 into preserved buffers
    spmm_prop<<<GBLK2, 64, 0, stream>>>(xs, x13b, row_ptr, (const ERec*)er, dinv);
    spmm_prop<<<GBLK2, 64, 0, stream>>>(x13b, x14b, row_ptr, (const ERec*)er, dinv);
    spmm_prop<<<GBLK2, 64, 0, stream>>>(x14b, x15b, row_ptr, (const ERec*)er, dinv);
    // final: acc = A*x15 (=x16), combine x16,x15,x14,x13,y0,bias -> out
    spmm_final<<<GBLK2, 64, 0, stream>>>(x15b, x13b, x14b, y0, b, row_ptr,
                                         (const ERec*)er, dinv, out);
}

// Round 2
// 570.924 us; speedup vs baseline: 1.5274x; 1.5274x over previous
//
#include <hip/hip_runtime.h>
#include <hip/hip_fp16.h>

#define NN 100000
#define EE 1200000
#define DD 64
#define CC 40
#define KK 16
#define BSZ 196                          // nodes per sort bucket
#define NBK 512                          // buckets (512*196 = 100352 >= NN)
#define TCAP 3072                        // tmp capacity per bucket (mean 2352, ~15 sigma)
#define EPB 4096                         // edges per phase-A block
#define ABLK ((EE + EPB - 1) / EPB)      // 293

// x layout per state buffer (float4 = 8 halves = 8 channels):
//   P01: [0, 2N)       node n -> {2n, 2n+1}   (channels 0..15, 32B/node)
//   P23: [2N, 4N)      node n -> {2n, 2n+1}+2N (channels 16..31)
//   P4 : [4N, 5N)      node n -> 4N + n        (channels 32..39)
// XCD pinning (block b -> XCD b%8, CDNA4 round-robin dispatch):
//   XCD 0..2 -> group01, node thirds;  XCD 3..5 -> group23, node thirds;
//   XCD 6..7 -> group4, node halves.
// Per-XCD gather working set: 3.2MB (pair) / 1.6MB (single) -> L2-resident.
#define NPX 1042                         // slots/XCD: ceil(33334/32)
#define NP4 782                          // ceil(50000/64)
#define GRID8 (8 * NPX)                  // 8336

// ---------- cursor init ----------
__global__ __launch_bounds__(512) void curinit_kernel(int* __restrict__ cursor) {
    int b = threadIdx.x;
    if (b < NBK) cursor[b] = b * TCAP;
}

// ---------- sort phase A: LDS-bin 4096 edges into 512 buckets ----------
__global__ __launch_bounds__(256) void sortA_kernel(const int* __restrict__ src,
                                                    const int* __restrict__ dst,
                                                    int* __restrict__ cursor,
                                                    int2* __restrict__ tmp) {
    __shared__ int2 stg[EPB];                 // 32KB
    __shared__ int hist[NBK], loff[NBK], lcur[NBK], gbase[NBK];  // 8KB
    int t = threadIdx.x;
    long e0 = (long)blockIdx.x * EPB;
    int n = (int)((EE - e0 < EPB) ? (EE - e0) : EPB);
    for (int j = t; j < NBK; j += 256) hist[j] = 0;
    __syncthreads();
    int d[16], sx[16];
#pragma unroll
    for (int j = 0; j < 16; ++j) {
        int i = t + j * 256;
        if (i < n) {
            d[j] = dst[e0 + i];
            sx[j] = src[e0 + i];
            atomicAdd(&hist[d[j] / BSZ], 1);
        } else d[j] = -1;
    }
    __syncthreads();
    int c0 = hist[2 * t], c1 = hist[2 * t + 1];
    int s2 = c0 + c1;
    __syncthreads();
    loff[t] = s2;
    __syncthreads();
    for (int off = 1; off < 256; off <<= 1) {
        int u = (t >= off) ? loff[t - off] : 0;
        __syncthreads();
        loff[t] += u;
        __syncthreads();
    }
    int excl = loff[t] - s2;
    __syncthreads();
    loff[2 * t] = excl;          loff[2 * t + 1] = excl + c0;
    lcur[2 * t] = excl;          lcur[2 * t + 1] = excl + c0;
    gbase[2 * t]     = atomicAdd(&cursor[2 * t], c0);
    gbase[2 * t + 1] = atomicAdd(&cursor[2 * t + 1], c1);
    __syncthreads();
#pragma unroll
    for (int j = 0; j < 16; ++j) {
        if (d[j] >= 0) {
            int b = d[j] / BSZ;
            int p = atomicAdd(&lcur[b], 1);
            stg[p] = make_int2(d[j], sx[j]);
        }
    }
    __syncthreads();
    for (int i = t; i < n; i += 256) {
        int2 r = stg[i];
        int b = r.x / BSZ;
        int pos = gbase[b] + (i - loff[b]);
        if (pos < (b + 1) * TCAP) tmp[pos] = r;  // overflow guard (never hit)
    }
}

// ---------- bucket-base scan ----------
__global__ __launch_bounds__(512) void bscan_kernel(const int* __restrict__ cursor,
                                                    int* __restrict__ bbase,
                                                    int* __restrict__ row_ptr) {
    __shared__ int sm[512];
    int t = threadIdx.x;
    int v = (t < NBK) ? (cursor[t] - t * TCAP) : 0;
    sm[t] = v;
    __syncthreads();
    for (int off = 1; off < 512; off <<= 1) {
        int u = (t >= off) ? sm[t - off] : 0;
        __syncthreads();
        sm[t] += u;
        __syncthreads();
    }
    if (t < NBK) bbase[t] = sm[t] - v;
    if (t == 511) row_ptr[NN] = sm[511];  // == EE
}

// ---------- sort phase B: counting sort within bucket; emit src-only edges ----------
__global__ __launch_bounds__(256) void sortB_kernel(const int2* __restrict__ tmp,
                                                    const int* __restrict__ cursor,
                                                    const int* __restrict__ bbase,
                                                    float* __restrict__ dinv,
                                                    float* __restrict__ sqd,
                                                    int* __restrict__ row_ptr,
                                                    int* __restrict__ er_src) {
    __shared__ int2 se[TCAP];     // 24KB
    __shared__ int so[TCAP];      // 12KB (src only)
    __shared__ int hist[256], lcur[256];
    int b = blockIdx.x;
    int n0 = b * BSZ;
    if (n0 >= NN) return;
    int n1 = n0 + BSZ; if (n1 > NN) n1 = NN;
    int nb = n1 - n0;
    int t = threadIdx.x;
    int cnt = cursor[b] - b * TCAP;
    int base = bbase[b];
    hist[t] = 0;
    __syncthreads();
    for (int i = t; i < cnt; i += 256) {
        int2 r = tmp[b * TCAP + i];
        se[i] = r;
        atomicAdd(&hist[r.x - n0], 1);
    }
    __syncthreads();
    if (t < nb) {
        float dg = (float)(hist[t] + 1);   // +1 self-loop
        dinv[n0 + t] = rsqrtf(dg);
        sqd[n0 + t]  = sqrtf(dg);
    }
    int v = hist[t];
    lcur[t] = v;
    __syncthreads();
    for (int off = 1; off < 256; off <<= 1) {
        int u = (t >= off) ? lcur[t - off] : 0;
        __syncthreads();
        lcur[t] += u;
        __syncthreads();
    }
    int excl = lcur[t] - v;
    __syncthreads();
    lcur[t] = excl;
    if (t < nb) row_ptr[n0 + t] = base + excl;
    __syncthreads();
    for (int i = t; i < cnt; i += 256) {
        int2 r = se[i];
        int ln = r.x - n0;
        int pos = atomicAdd(&lcur[ln], 1);
        so[pos] = r.y;                    // src only (z-space: weights folded out)
    }
    __syncthreads();
    for (int i = t; i < cnt; i += 256) er_src[base + i] = so[i];  // coalesced
}

// ---------- projection: z0 = dinv * (feat @ W^T), stored in P-layout ----------
__global__ __launch_bounds__(256) void proj_kernel(const float4* __restrict__ feat4,
                                                   const float* __restrict__ W,
                                                   const float* __restrict__ dinv,
                                                   float4* __restrict__ z0) {
    __shared__ float smW[CC * 68];   // 10.9KB
    __shared__ float smF[64 * 68];   // 17.4KB
    __shared__ float smO[64 * 42];   // 10.8KB
    int t = threadIdx.x;
    for (int j = t; j < CC * 16; j += 256) {
        int c = j >> 4, q = j & 15;
        *(float4*)(smW + c * 68 + q * 4) = ((const float4*)W)[j];
    }
    int n0 = blockIdx.x * 64;
    for (int j = t; j < 64 * 16; j += 256) {
        int r = j >> 4, q = j & 15;
        if (n0 + r < NN)
            *(float4*)(smF + r * 68 + q * 4) = feat4[(size_t)(n0 + r) * 16 + q];
    }
    __syncthreads();
    int ln = t >> 2, c0 = (t & 3) * 10;
    int node = n0 + ln;
    float acc[10];
#pragma unroll
    for (int c = 0; c < 10; ++c) acc[c] = 0.f;
    if (node < NN) {
#pragma unroll
        for (int db = 0; db < 16; ++db) {
            float4 fv = *(const float4*)(smF + ln * 68 + db * 4);
#pragma unroll
            for (int c = 0; c < 10; ++c) {
                float4 wv = *(const float4*)(smW + (c0 + c) * 68 + db * 4);
                acc[c] = fmaf(fv.x, wv.x, acc[c]);
                acc[c] = fmaf(fv.y, wv.y, acc[c]);
                acc[c] = fmaf(fv.z, wv.z, acc[c]);
                acc[c] = fmaf(fv.w, wv.w, acc[c]);
            }
        }
    }
#pragma unroll
    for (int c = 0; c < 10; ++c) smO[ln * 42 + c0 + c] = acc[c];
    __syncthreads();
    for (int j = t; j < 64 * 5; j += 256) {
        int r = j & 63, q = j >> 6;
        int g = n0 + r;
        if (g < NN) {
            float dv = dinv[g];
            const float* s = smO + r * 42 + q * 8;
            float4 ov;
            __half2* op = (__half2*)&ov;
            op[0] = __floats2half2_rn(dv * s[0], dv * s[1]);
            op[1] = __floats2half2_rn(dv * s[2], dv * s[3]);
            op[2] = __floats2half2_rn(dv * s[4], dv * s[5]);
            op[3] = __floats2half2_rn(dv * s[6], dv * s[7]);
            size_t idx = (q < 2) ? ((size_t)g * 2 + q)
                       : (q < 4) ? ((size_t)2 * NN + (size_t)g * 2 + (q - 2))
                                 : ((size_t)4 * NN + g);
            z0[idx] = ov;
        }
    }
}

// decode float4-of-8-halves into 8 floats
#define DEC8(V, F0, F1, F2, F3)                                             \
    const __half2* hp_##F0 = (const __half2*)&(V);                          \
    float2 F0 = __half22float2(hp_##F0[0]), F1 = __half22float2(hp_##F0[1]);\
    float2 F2 = __half22float2(hp_##F0[2]), F3 = __half22float2(hp_##F0[3]);

#define ACC8U(V)                                                            \
    {                                                                       \
        DEC8(V, f0, f1, f2, f3)                                             \
        a0 += f0.x; a1 += f0.y; a2 += f1.x; a3 += f1.y;                     \
        a4 += f2.x; a5 += f2.y; a6 += f3.x; a7 += f3.y;                     \
    }

// unweighted gather loop over src-only records; up to 8 gathers in flight/lane
#define GLOOP(XP, STR, PL)                                                  \
    int e = beg;                                                            \
    int e8 = beg + ((end - beg) & ~7);                                      \
    for (; e < e8; e += 8) {                                                \
        int s0 = es[e], s1 = es[e + 1], s2 = es[e + 2], s3 = es[e + 3];     \
        int s4 = es[e + 4], s5 = es[e + 5], s6 = es[e + 6], s7 = es[e + 7]; \
        float4 v0 = (XP)[s0 * (STR) + (PL)];                                \
        float4 v1 = (XP)[s1 * (STR) + (PL)];                                \
        float4 v2 = (XP)[s2 * (STR) + (PL)];                                \
        float4 v3 = (XP)[s3 * (STR) + (PL)];                                \
        float4 v4 = (XP)[s4 * (STR) + (PL)];                                \
        float4 v5 = (XP)[s5 * (STR) + (PL)];                                \
        float4 v6 = (XP)[s6 * (STR) + (PL)];                                \
        float4 v7 = (XP)[s7 * (STR) + (PL)];                                \
        ACC8U(v0); ACC8U(v1); ACC8U(v2); ACC8U(v3);                         \
        ACC8U(v4); ACC8U(v5); ACC8U(v6); ACC8U(v7);                         \
    }                                                                       \
    int e4 = e + ((end - e) & ~3);                                          \
    for (; e < e4; e += 4) {                                                \
        int s0 = es[e], s1 = es[e + 1], s2 = es[e + 2], s3 = es[e + 3];     \
        float4 v0 = (XP)[s0 * (STR) + (PL)];                                \
        float4 v1 = (XP)[s1 * (STR) + (PL)];                                \
        float4 v2 = (XP)[s2 * (STR) + (PL)];                                \
        float4 v3 = (XP)[s3 * (STR) + (PL)];                                \
        ACC8U(v0); ACC8U(v1); ACC8U(v2); ACC8U(v3);                         \
    }                                                                       \
    for (; e < end; ++e) {                                                  \
        int s = es[e];                                                      \
        float4 v = (XP)[s * (STR) + (PL)];                                  \
        ACC8U(v);                                                           \
    }

// ---------- SpMM propagate body: z_out[d] = dinv[d]^2 * (z[d] + sum z[src]) ----------
template <int STR>
__device__ __forceinline__ void prop_body(
    int g, int pl, size_t off,
    const float4* __restrict__ x, float4* __restrict__ x_out,
    const int* __restrict__ row_ptr, const int* __restrict__ es,
    const float* __restrict__ dinv) {
    const float4* xp = x + off;
    int beg = row_ptr[g], end = row_ptr[g + 1];
    float di = dinv[g];
    float w2 = di * di;
    int sb = g * STR + pl;
    float4 sv = xp[sb];
    float a0, a1, a2, a3, a4, a5, a6, a7;
    {
        DEC8(sv, f0, f1, f2, f3)
        a0 = f0.x; a1 = f0.y; a2 = f1.x; a3 = f1.y;
        a4 = f2.x; a5 = f2.y; a6 = f3.x; a7 = f3.y;
    }
    GLOOP(xp, STR, pl)
    float4 ov;
    __half2* op = (__half2*)&ov;
    op[0] = __floats2half2_rn(w2 * a0, w2 * a1);
    op[1] = __floats2half2_rn(w2 * a2, w2 * a3);
    op[2] = __floats2half2_rn(w2 * a4, w2 * a5);
    op[3] = __floats2half2_rn(w2 * a6, w2 * a7);
    x_out[off + sb] = ov;
}

// block -> (work). XCD k = blockIdx%8. Returns via template dispatch.
__global__ __launch_bounds__(64) void spmm_prop(
    const float4* __restrict__ x, float4* __restrict__ x_out,
    const int* __restrict__ row_ptr, const int* __restrict__ es,
    const float* __restrict__ dinv) {
    int xcd = blockIdx.x & 7;
    int slot = blockIdx.x >> 3;
    int lane = threadIdx.x;
    if (xcd < 6) {
        int part = (xcd < 3) ? xcd : xcd - 3;
        int grp  = (xcd < 3) ? 0 : 1;
        int b0 = (part == 0) ? 0 : ((part == 1) ? 33334 : 66667);
        int b1 = (part == 0) ? 33334 : ((part == 1) ? 66667 : 100000);
        int g = b0 + slot * 32 + (lane >> 1);
        if (g >= b1) return;
        prop_body<2>(g, lane & 1, (size_t)grp * 2 * NN, x, x_out, row_ptr, es, dinv);
    } else {
        if (slot >= NP4) return;
        int b0 = (xcd - 6) * 50000;
        int g = b0 + slot * 64 + lane;
        if (g >= b0 + 50000) return;
        prop_body<1>(g, 0, (size_t)4 * NN, x, x_out, row_ptr, es, dinv);
    }
}

// ---------- final: acc = sum z15 (incl self); out = C16*dinv*acc
//            + sqd*(C15*z15 + C14*z14 + C13*z13 + FC*z0) + bias ----------
template <int STR>
__device__ __forceinline__ void final_body(
    int g, int pl, int p, size_t off,
    const float4* __restrict__ x15, const float4* __restrict__ x13p,
    const float4* __restrict__ x14p, const float4* __restrict__ z0p,
    const float* __restrict__ bias,
    const int* __restrict__ row_ptr, const int* __restrict__ es,
    const float* __restrict__ dinv, const float* __restrict__ sqd,
    float* __restrict__ outp) {
    const float4* xp = x15 + off;
    int beg = row_ptr[g], end = row_ptr[g + 1];
    float di = dinv[g];
    float sq = sqd[g];
    int sb = g * STR + pl;
    size_t gi = off + sb;
    float4 sv = xp[sb];
    float s0, s1, s2, s3, s4, s5, s6, s7;
    float a0, a1, a2, a3, a4, a5, a6, a7;
    {
        DEC8(sv, f0, f1, f2, f3)
        s0 = f0.x; s1 = f0.y; s2 = f1.x; s3 = f1.y;
        s4 = f2.x; s5 = f2.y; s6 = f3.x; s7 = f3.y;
        a0 = s0; a1 = s1; a2 = s2; a3 = s3;
        a4 = s4; a5 = s5; a6 = s6; a7 = s7;
    }
    GLOOP(xp, STR, pl)
    const float C16 = 0.95f / 16.0f;
    const float C15 = 0.95f / 256.0f;
    const float C14 = 0.95f / 4096.0f;
    const float C13 = 0.95f / 65536.0f;
    const float FC  = 0.05f / 15.0f;
    float t0 = C15 * s0, t1 = C15 * s1, t2 = C15 * s2, t3 = C15 * s3;
    float t4 = C15 * s4, t5 = C15 * s5, t6 = C15 * s6, t7 = C15 * s7;
#define ADD8T(P, CF)                                                        \
    {                                                                       \
        float4 v = (P)[gi];                                                 \
        DEC8(v, f0, f1, f2, f3)                                             \
        t0 = fmaf((CF), f0.x, t0); t1 = fmaf((CF), f0.y, t1);               \
        t2 = fmaf((CF), f1.x, t2); t3 = fmaf((CF), f1.y, t3);               \
        t4 = fmaf((CF), f2.x, t4); t5 = fmaf((CF), f2.y, t5);               \
        t6 = fmaf((CF), f3.x, t6); t7 = fmaf((CF), f3.y, t7);               \
    }
    ADD8T(x14p, C14)
    ADD8T(x13p, C13)
    ADD8T(z0p, FC)
#undef ADD8T
    float cd = C16 * di;
    float o0 = fmaf(sq, t0, cd * a0), o1 = fmaf(sq, t1, cd * a1);
    float o2 = fmaf(sq, t2, cd * a2), o3 = fmaf(sq, t3, cd * a3);
    float o4 = fmaf(sq, t4, cd * a4), o5 = fmaf(sq, t5, cd * a5);
    float o6 = fmaf(sq, t6, cd * a6), o7 = fmaf(sq, t7, cd * a7);
    const float4* b4 = (const float4*)(bias + p * 8);
    float4 bb0 = b4[0], bb1 = b4[1];
    float4* op = (float4*)(outp + (size_t)g * CC + p * 8);
    op[0] = make_float4(o0 + bb0.x, o1 + bb0.y, o2 + bb0.z, o3 + bb0.w);
    op[1] = make_float4(o4 + bb1.x, o5 + bb1.y, o6 + bb1.z, o7 + bb1.w);
}

__global__ __launch_bounds__(64) void spmm_final(
    const float4* __restrict__ x15, const float4* __restrict__ x13p,
    const float4* __restrict__ x14p, const float4* __restrict__ z0p,
    const float* __restrict__ bias,
    const int* __restrict__ row_ptr, const int* __restrict__ es,
    const float* __restrict__ dinv, const float* __restrict__ sqd,
    float* __restrict__ outp) {
    int xcd = blockIdx.x & 7;
    int slot = blockIdx.x >> 3;
    int lane = threadIdx.x;
    if (xcd < 6) {
        int part = (xcd < 3) ? xcd : xcd - 3;
        int grp  = (xcd < 3) ? 0 : 1;
        int b0 = (part == 0) ? 0 : ((part == 1) ? 33334 : 66667);
        int b1 = (part == 0) ? 33334 : ((part == 1) ? 66667 : 100000);
        int g = b0 + slot * 32 + (lane >> 1);
        if (g >= b1) return;
        int pl = lane & 1;
        final_body<2>(g, pl, grp * 2 + pl, (size_t)grp * 2 * NN,
                      x15, x13p, x14p, z0p, bias, row_ptr, es, dinv, sqd, outp);
    } else {
        if (slot >= NP4) return;
        int b0 = (xcd - 6) * 50000;
        int g = b0 + slot * 64 + lane;
        if (g >= b0 + 50000) return;
        final_body<1>(g, 0, 4, (size_t)4 * NN,
                      x15, x13p, x14p, z0p, bias, row_ptr, es, dinv, sqd, outp);
    }
}

extern "C" void kernel_launch(void* const* d_in, const int* in_sizes, int n_in,
                              void* d_out, int out_size, void* d_ws, size_t ws_size,
                              hipStream_t stream) {
    const float* feat = (const float*)d_in[0];
    const float* W    = (const float*)d_in[1];
    const float* b    = (const float*)d_in[2];
    const int*   src  = (const int*)d_in[3];
    const int*   dst  = (const int*)d_in[4];
    float* out = (float*)d_out;

    char* p = (char*)d_ws;
    auto alloc = [&](size_t bytes) {
        char* r = p;
        p += (bytes + 255) & ~(size_t)255;
        return r;
    };
    float*   dinv    = (float*)alloc((size_t)NN * sizeof(float));
    float*   sqd     = (float*)alloc((size_t)NN * sizeof(float));
    int*     row_ptr = (int*)alloc((size_t)(NN + 1) * sizeof(int));
    int*     cursor  = (int*)alloc((size_t)NBK * sizeof(int));
    int*     bbase   = (int*)alloc((size_t)NBK * sizeof(int));
    int2*    tmp     = (int2*)alloc((size_t)NBK * TCAP * sizeof(int2));  // 12.6MB
    int*     er_src  = (int*)alloc((size_t)EE * sizeof(int));            // 4.8MB
    float4*  z0      = (float4*)alloc((size_t)NN * 5 * sizeof(float4));  // 8MB
    float4*  xa      = (float4*)alloc((size_t)NN * 5 * sizeof(float4));  // 8MB
    float4*  xb      = (float4*)alloc((size_t)NN * 5 * sizeof(float4));  // 8MB
    float4*  z13     = (float4*)alloc((size_t)NN * 5 * sizeof(float4));  // 8MB
    float4*  z14     = (float4*)alloc((size_t)NN * 5 * sizeof(float4));  // 8MB
    float4*  z15     = (float4*)alloc((size_t)NN * 5 * sizeof(float4));  // 8MB

    curinit_kernel<<<1, 512, 0, stream>>>(cursor);
    sortA_kernel<<<ABLK, 256, 0, stream>>>(src, dst, cursor, tmp);
    bscan_kernel<<<1, 512, 0, stream>>>(cursor, bbase, row_ptr);
    sortB_kernel<<<NBK, 256, 0, stream>>>(tmp, cursor, bbase, dinv, sqd, row_ptr, er_src);
    proj_kernel<<<(NN + 63) / 64, 256, 0, stream>>>((const float4*)feat, W, dinv, z0);

    // z1..z12: ping-pong xa/xb
    const float4* xs = z0;
    for (int j = 0; j < 12; ++j) {
        float4* xd = (j & 1) ? xb : xa;
        spmm_prop<<<GRID8, 64, 0, stream>>>(xs, xd, row_ptr, er_src, dinv);
        xs = xd;
    }
    // z13, z14, z15 into preserved buffers
    spmm_prop<<<GRID8, 64, 0, stream>>>(xs, z13, row_ptr, er_src, dinv);
    spmm_prop<<<GRID8, 64, 0, stream>>>(z13, z14, row_ptr, er_src, dinv);
    spmm_prop<<<GRID8, 64, 0, stream>>>(z14, z15, row_ptr, er_src, dinv);
    // final combine
    spmm_final<<<GRID8, 64, 0, stream>>>(z15, z13, z14, z0, b, row_ptr,
                                         er_src, dinv, sqd, out);
}